// Round 1
// baseline (1828.675 us; speedup 1.0000x reference)
//
#include <hip/hip_runtime.h>
#include <math.h>

// Sizes (fixed by problem): D=256, H=8, HD=32, FE=64. N, E taken from in_sizes.

// ---------------------------------------------------------------------------
// GEMM: C[M x 256] = A[M x 256] @ W[256 x 256] (+ bias). fp32, 64x64 tile.
// ---------------------------------------------------------------------------
__global__ __launch_bounds__(256) void gemm256(const float* __restrict__ A,
                                               const float* __restrict__ W,
                                               const float* __restrict__ bias,
                                               float* __restrict__ C, int M) {
    const int K = 256;
    __shared__ float As[16][68];
    __shared__ float Ws[16][68];
    int t  = threadIdx.x;
    int bm = blockIdx.x * 64;
    int bn = blockIdx.y * 64;
    int tx = t & 15, ty = t >> 4;
    float acc[4][4] = {};

    int la_m = t >> 2;       // 0..63  (A row within tile)
    int la_k = (t & 3) * 4;  // 0,4,8,12
    int lw_k = t >> 4;       // 0..15
    int lw_n = (t & 15) * 4; // 0..60

    for (int k0 = 0; k0 < K; k0 += 16) {
        float4 av;
        int gm = bm + la_m;
        if (gm < M) av = *(const float4*)&A[(size_t)gm * K + k0 + la_k];
        else        av = make_float4(0.f, 0.f, 0.f, 0.f);
        As[la_k + 0][la_m] = av.x;
        As[la_k + 1][la_m] = av.y;
        As[la_k + 2][la_m] = av.z;
        As[la_k + 3][la_m] = av.w;
        float4 wv = *(const float4*)&W[(size_t)(k0 + lw_k) * K + bn + lw_n];
        *(float4*)&Ws[lw_k][lw_n] = wv;
        __syncthreads();
#pragma unroll
        for (int kk = 0; kk < 16; ++kk) {
            float4 a4 = *(const float4*)&As[kk][ty * 4];
            float4 w4 = *(const float4*)&Ws[kk][tx * 4];
            float am[4] = {a4.x, a4.y, a4.z, a4.w};
            float wn[4] = {w4.x, w4.y, w4.z, w4.w};
#pragma unroll
            for (int i = 0; i < 4; ++i)
#pragma unroll
                for (int j = 0; j < 4; ++j)
                    acc[i][j] += am[i] * wn[j];
        }
        __syncthreads();
    }
#pragma unroll
    for (int i = 0; i < 4; ++i) {
        int gm = bm + ty * 4 + i;
        if (gm >= M) continue;
#pragma unroll
        for (int j = 0; j < 4; ++j) {
            int gn = bn + tx * 4 + j;
            float v = acc[i][j];
            if (bias) v += bias[gn];
            C[(size_t)gm * 256 + gn] = v;
        }
    }
}

// ---------------------------------------------------------------------------
// Edge MLP: mlp[e][h] = relu(efeat[e] @ W1 + b1) @ W2.  64 edges per block.
// efeat (E x 64), W1 (64 x 256), W2 (256 x 8).
// ---------------------------------------------------------------------------
__global__ __launch_bounds__(256) void edge_mlp(const float* __restrict__ efeat,
                                                const float* __restrict__ W1,
                                                const float* __restrict__ b1,
                                                const float* __restrict__ W2,
                                                float* __restrict__ mlp, int E) {
    __shared__ float efsT[64][68];  // [k][e]
    __shared__ float W2s[256 * 8];  // [j*8+h]
    __shared__ float b1s[256];
    int t  = threadIdx.x;
    int e0 = blockIdx.x * 64;

    { // stage efeat tile transposed
        int e = t >> 2;
        int q = t & 3;
        int ge = e0 + e;
#pragma unroll
        for (int u = 0; u < 4; ++u) {
            float4 v;
            if (ge < E) v = *(const float4*)&efeat[(size_t)ge * 64 + q * 16 + u * 4];
            else        v = make_float4(0.f, 0.f, 0.f, 0.f);
            int k = q * 16 + u * 4;
            efsT[k + 0][e] = v.x;
            efsT[k + 1][e] = v.y;
            efsT[k + 2][e] = v.z;
            efsT[k + 3][e] = v.w;
        }
#pragma unroll
        for (int u = 0; u < 8; ++u) W2s[t * 8 + u] = W2[t * 8 + u];
        b1s[t] = b1[t];
    }
    __syncthreads();

    int eg = t >> 4;  // 0..15 -> edges eg*4..+3
    int jg = t & 15;  // cols jg*16..+15
    float acc[4][16] = {};

#pragma unroll 2
    for (int k = 0; k < 64; ++k) {
        float4 a = *(const float4*)&efsT[k][eg * 4];
        const float* wrow = &W1[(size_t)k * 256 + jg * 16];
        float4 w0 = *(const float4*)&wrow[0];
        float4 w1v = *(const float4*)&wrow[4];
        float4 w2v = *(const float4*)&wrow[8];
        float4 w3v = *(const float4*)&wrow[12];
        float ae[4] = {a.x, a.y, a.z, a.w};
        float wj[16] = {w0.x, w0.y, w0.z, w0.w, w1v.x, w1v.y, w1v.z, w1v.w,
                        w2v.x, w2v.y, w2v.z, w2v.w, w3v.x, w3v.y, w3v.z, w3v.w};
#pragma unroll
        for (int i = 0; i < 4; ++i)
#pragma unroll
            for (int j = 0; j < 16; ++j)
                acc[i][j] += ae[i] * wj[j];
    }

    // relu + @W2 epilogue
    float sc[4][8] = {};
#pragma unroll
    for (int j = 0; j < 16; ++j) {
        int gj = jg * 16 + j;
        float bj = b1s[gj];
#pragma unroll
        for (int i = 0; i < 4; ++i) {
            float r = fmaxf(acc[i][j] + bj, 0.f);
#pragma unroll
            for (int h = 0; h < 8; ++h) sc[i][h] += r * W2s[gj * 8 + h];
        }
    }
    // reduce across the 16 lanes sharing an edge group (consecutive lanes)
#pragma unroll
    for (int off = 1; off < 16; off <<= 1) {
#pragma unroll
        for (int i = 0; i < 4; ++i)
#pragma unroll
            for (int h = 0; h < 8; ++h)
                sc[i][h] += __shfl_xor(sc[i][h], off, 64);
    }
    if (jg == 0) {
#pragma unroll
        for (int i = 0; i < 4; ++i) {
            int ge = e0 + eg * 4 + i;
            if (ge < E) {
#pragma unroll
                for (int h = 0; h < 8; ++h) mlp[(size_t)ge * 8 + h] = sc[i][h];
            }
        }
    }
}

// ---------------------------------------------------------------------------
// CSR build
// ---------------------------------------------------------------------------
__global__ void count_edges(const int* __restrict__ dst, int* counts, int E) {
    int e = blockIdx.x * 256 + threadIdx.x;
    if (e < E) atomicAdd(&counts[dst[e]], 1);
}

__global__ __launch_bounds__(1024) void scan_counts(const int* __restrict__ counts,
                                                    int* indptr, int* fill, int n) {
    __shared__ int sm[1024];
    __shared__ int carry_s;
    int t = threadIdx.x;
    if (t == 0) carry_s = 0;
    __syncthreads();
    for (int base = 0; base < n; base += 1024) {
        int i = base + t;
        int v = (i < n) ? counts[i] : 0;
        sm[t] = v;
        __syncthreads();
        for (int off = 1; off < 1024; off <<= 1) {
            int u = (t >= off) ? sm[t - off] : 0;
            __syncthreads();
            sm[t] += u;
            __syncthreads();
        }
        int carry = carry_s;
        int excl  = carry + sm[t] - v;
        if (i < n) { indptr[i] = excl; fill[i] = excl; }
        __syncthreads();
        if (t == 1023) carry_s = carry + sm[1023];
        __syncthreads();
    }
    if (t == 0) indptr[n] = carry_s;
}

__global__ void scatter_edges(const int* __restrict__ dst, int* fill,
                              int* edge_ids, int E) {
    int e = blockIdx.x * 256 + threadIdx.x;
    if (e < E) {
        int pos = atomicAdd(&fill[dst[e]], 1);
        edge_ids[pos] = e;
    }
}

// ---------------------------------------------------------------------------
// Per-node fused: QK dot + mlp bias + exp + denom + alpha*V aggregation.
// One wave per dst node. Softmax without max-subtraction (scores bounded ~|8|).
// ---------------------------------------------------------------------------
__global__ __launch_bounds__(64) void node_aggregate(
        const float* __restrict__ Q, const float* __restrict__ K,
        const float* __restrict__ V, const float* __restrict__ mlp,
        const float* __restrict__ b2, const int* __restrict__ src,
        const int* __restrict__ indptr, const int* __restrict__ edge_ids,
        float* __restrict__ outp, int Nn) {
    int b = blockIdx.x;
    if (b >= Nn) return;
    int lane = threadIdx.x;
    int g = lane >> 3;  // head: lanes l cover dims l*4..l*4+3, head = (l*4)/32
    float4 q4 = *(const float4*)&Q[(size_t)b * 256 + lane * 4];
    float bb = b2[g];
    int beg = indptr[b], end = indptr[b + 1];
    float o0 = 0.f, o1 = 0.f, o2 = 0.f, o3 = 0.f;
    float den = 0.f;
    const float inv_sqrt = 0.17677669529663687f;  // 1/sqrt(32)
    for (int idx = beg; idx < end; ++idx) {
        int e = edge_ids[idx];
        int s = src[e];
        float4 k4 = *(const float4*)&K[(size_t)s * 256 + lane * 4];
        float4 v4 = *(const float4*)&V[(size_t)s * 256 + lane * 4];
        float part = q4.x * k4.x + q4.y * k4.y + q4.z * k4.z + q4.w * k4.w;
        part += __shfl_xor(part, 1, 64);
        part += __shfl_xor(part, 2, 64);
        part += __shfl_xor(part, 4, 64);
        float scv = part * inv_sqrt + mlp[(size_t)e * 8 + g] + bb;
        float p = __expf(scv);
        den += p;
        o0 += p * v4.x; o1 += p * v4.y; o2 += p * v4.z; o3 += p * v4.w;
    }
    float invd = (end > beg) ? 1.f / den : 0.f;
    float4 ov = make_float4(o0 * invd, o1 * invd, o2 * invd, o3 * invd);
    *(float4*)&outp[(size_t)b * 256 + lane * 4] = ov;
}

// ---------------------------------------------------------------------------
extern "C" void kernel_launch(void* const* d_in, const int* in_sizes, int n_in,
                              void* d_out, int out_size, void* d_ws, size_t ws_size,
                              hipStream_t stream) {
    const float* h     = (const float*)d_in[0];
    const float* efeat = (const float*)d_in[1];
    const int*   src   = (const int*)d_in[2];
    const int*   dst   = (const int*)d_in[3];
    const float* Wq    = (const float*)d_in[4];
    const float* Wk    = (const float*)d_in[5];
    const float* Wv    = (const float*)d_in[6];
    const float* W1    = (const float*)d_in[7];
    const float* b1    = (const float*)d_in[8];
    const float* W2    = (const float*)d_in[9];
    const float* b2    = (const float*)d_in[10];
    const float* Wo    = (const float*)d_in[11];
    const float* bo    = (const float*)d_in[12];
    float* out = (float*)d_out;

    const int N = in_sizes[0] / 256;
    const int E = in_sizes[2];

    // workspace carve (all 256B aligned)
    char* p = (char*)d_ws;
    auto carve = [&](size_t bytes) {
        char* r = p;
        p += (bytes + 255) & ~(size_t)255;
        return (void*)r;
    };
    float* Q      = (float*)carve((size_t)N * 256 * 4);
    float* Kp     = (float*)carve((size_t)N * 256 * 4);
    float* Vp     = (float*)carve((size_t)N * 256 * 4);
    float* mlp    = (float*)carve((size_t)E * 8 * 4);
    float* outp   = (float*)carve((size_t)N * 256 * 4);
    int* counts   = (int*)carve((size_t)N * 4);
    int* indptr   = (int*)carve((size_t)(N + 1) * 4);
    int* fill     = (int*)carve((size_t)N * 4);
    int* edge_ids = (int*)carve((size_t)E * 4);

    hipMemsetAsync(counts, 0, (size_t)N * 4, stream);

    dim3 gg((N + 63) / 64, 4);
    gemm256<<<gg, 256, 0, stream>>>(h, Wq, nullptr, Q, N);
    gemm256<<<gg, 256, 0, stream>>>(h, Wk, nullptr, Kp, N);
    gemm256<<<gg, 256, 0, stream>>>(h, Wv, nullptr, Vp, N);
    edge_mlp<<<(E + 63) / 64, 256, 0, stream>>>(efeat, W1, b1, W2, mlp, E);
    count_edges<<<(E + 255) / 256, 256, 0, stream>>>(dst, counts, E);
    scan_counts<<<1, 1024, 0, stream>>>(counts, indptr, fill, N);
    scatter_edges<<<(E + 255) / 256, 256, 0, stream>>>(dst, fill, edge_ids, E);
    node_aggregate<<<N, 64, 0, stream>>>(Q, Kp, Vp, mlp, b2, src, indptr, edge_ids, outp, N);
    gemm256<<<gg, 256, 0, stream>>>(outp, Wo, bo, out, N);
}

// Round 2
// 1247.894 us; speedup vs baseline: 1.4654x; 1.4654x over previous
//
#include <hip/hip_runtime.h>
#include <math.h>

// Sizes fixed by problem: D=256, H=8, HD=32, FE=64. N, E from in_sizes.

typedef short s8v __attribute__((ext_vector_type(8)));   // 8 bf16 (4 VGPR)
typedef float f32x4 __attribute__((ext_vector_type(4))); // MFMA acc

__device__ inline unsigned short f2bf(float x) {
    unsigned int u = __float_as_uint(x);
    unsigned int r = u + 0x7FFFu + ((u >> 16) & 1u);  // RNE
    return (unsigned short)(r >> 16);
}
__device__ inline float bf2f(unsigned short b) {
    return __uint_as_float(((unsigned int)b) << 16);
}

// ---------------------------------------------------------------------------
// GEMM: C[M x 256] = A[M x 256] @ W[256 x 256] (+ bias). fp32 (unchanged).
// ---------------------------------------------------------------------------
__global__ __launch_bounds__(256) void gemm256(const float* __restrict__ A,
                                               const float* __restrict__ W,
                                               const float* __restrict__ bias,
                                               float* __restrict__ C, int M) {
    const int K = 256;
    __shared__ float As[16][68];
    __shared__ float Ws[16][68];
    int t  = threadIdx.x;
    int bm = blockIdx.x * 64;
    int bn = blockIdx.y * 64;
    int tx = t & 15, ty = t >> 4;
    float acc[4][4] = {};

    int la_m = t >> 2;
    int la_k = (t & 3) * 4;
    int lw_k = t >> 4;
    int lw_n = (t & 15) * 4;

    for (int k0 = 0; k0 < K; k0 += 16) {
        float4 av;
        int gm = bm + la_m;
        if (gm < M) av = *(const float4*)&A[(size_t)gm * K + k0 + la_k];
        else        av = make_float4(0.f, 0.f, 0.f, 0.f);
        As[la_k + 0][la_m] = av.x;
        As[la_k + 1][la_m] = av.y;
        As[la_k + 2][la_m] = av.z;
        As[la_k + 3][la_m] = av.w;
        float4 wv = *(const float4*)&W[(size_t)(k0 + lw_k) * K + bn + lw_n];
        *(float4*)&Ws[lw_k][lw_n] = wv;
        __syncthreads();
#pragma unroll
        for (int kk = 0; kk < 16; ++kk) {
            float4 a4 = *(const float4*)&As[kk][ty * 4];
            float4 w4 = *(const float4*)&Ws[kk][tx * 4];
            float am[4] = {a4.x, a4.y, a4.z, a4.w};
            float wn[4] = {w4.x, w4.y, w4.z, w4.w};
#pragma unroll
            for (int i = 0; i < 4; ++i)
#pragma unroll
                for (int j = 0; j < 4; ++j)
                    acc[i][j] += am[i] * wn[j];
        }
        __syncthreads();
    }
#pragma unroll
    for (int i = 0; i < 4; ++i) {
        int gm = bm + ty * 4 + i;
        if (gm >= M) continue;
#pragma unroll
        for (int j = 0; j < 4; ++j) {
            int gn = bn + tx * 4 + j;
            float v = acc[i][j];
            if (bias) v += bias[gn];
            C[(size_t)gm * 256 + gn] = v;
        }
    }
}

// ---------------------------------------------------------------------------
// Prep: W1 (64x256 fp32) -> MFMA B-frag order, bf16 hi/lo split.
// Frag layout: idx = ((kc*16+nc)*64 + lane)*8 + i  where
//   k = kc*32 + (lane>>4)*8 + i, col = nc*16 + (lane&15).
// ---------------------------------------------------------------------------
__global__ void prep_w1(const float* __restrict__ W1,
                        unsigned short* __restrict__ W1h,
                        unsigned short* __restrict__ W1l) {
    int f = blockIdx.x * 256 + threadIdx.x;  // 0..16383
    if (f >= 16384) return;
    int i    = f & 7;
    int lane = (f >> 3) & 63;
    int nc   = (f >> 9) & 15;
    int kc   = (f >> 13) & 1;
    int k    = kc * 32 + (lane >> 4) * 8 + i;
    int col  = nc * 16 + (lane & 15);
    float v = W1[k * 256 + col];
    unsigned short hb = f2bf(v);
    W1h[f] = hb;
    W1l[f] = f2bf(v - bf2f(hb));
}

// W2 (256x8 fp32) -> B-frag order bf16, N padded to 16 with zeros.
// idx = (kc*64 + lane)*8 + i; k = kc*32 + (lane>>4)*8 + i, col = lane&15.
__global__ void prep_w2(const float* __restrict__ W2,
                        unsigned short* __restrict__ W2f) {
    int f = blockIdx.x * 256 + threadIdx.x;  // 0..4095
    if (f >= 4096) return;
    int i    = f & 7;
    int lane = (f >> 3) & 63;
    int kc   = (f >> 9) & 7;
    int k    = kc * 32 + (lane >> 4) * 8 + i;
    int col  = lane & 15;
    float v = (col < 8) ? W2[k * 8 + col] : 0.f;
    W2f[f] = f2bf(v);
}

// ---------------------------------------------------------------------------
// Edge MLP via MFMA: mlp[e][h] = relu(efeat[e] @ W1 + b1) @ W2.
// Block = 64 edges, 4 waves. GEMM1 split-bf16 (3 MFMA per product),
// GEMM2 plain bf16. Hidden round-trips through padded LDS.
// ---------------------------------------------------------------------------
__global__ __launch_bounds__(256) void edge_mlp_mfma(
        const float* __restrict__ efeat,
        const unsigned short* __restrict__ W1h,
        const unsigned short* __restrict__ W1l,
        const unsigned short* __restrict__ W2f,
        const float* __restrict__ b1, const float* __restrict__ b2,
        float* __restrict__ mlp, int E) {
    __shared__ float efs[64][68];             // padded fp32 efeat tile
    __shared__ unsigned short hid[64][264];   // padded bf16 hidden tile
    __shared__ float b1s[256];
    int t  = threadIdx.x;
    int e0 = blockIdx.x * 64;

    // stage efeat tile (64 rows x 64 cols fp32)
    {
        int row = t >> 2, cq = (t & 3) * 16;
        int ge = e0 + row;
#pragma unroll
        for (int u = 0; u < 4; ++u) {
            float4 v;
            if (ge < E) v = *(const float4*)&efeat[(size_t)ge * 64 + cq + u * 4];
            else        v = make_float4(0.f, 0.f, 0.f, 0.f);
            *(float4*)&efs[row][cq + u * 4] = v;
        }
        b1s[t] = b1[t];
    }
    __syncthreads();

    int w = t >> 6;     // wave 0..3 -> hidden cols w*64..w*64+63
    int l = t & 63;
    int c = l & 15, g = l >> 4;

    // A-frags for 4 M-tiles (edges m*16+c), hi/lo split
    s8v Ah[4][2], Al[4][2];
#pragma unroll
    for (int m = 0; m < 4; ++m) {
        int row = m * 16 + c;
#pragma unroll
        for (int kc = 0; kc < 2; ++kc) {
            const float* p = &efs[row][kc * 32 + g * 8];
            float x[8];
            *(float4*)&x[0] = *(const float4*)&p[0];
            *(float4*)&x[4] = *(const float4*)&p[4];
            s8v hi, lo;
#pragma unroll
            for (int i = 0; i < 8; ++i) {
                unsigned short hb = f2bf(x[i]);
                hi[i] = (short)hb;
                lo[i] = (short)f2bf(x[i] - bf2f(hb));
            }
            Ah[m][kc] = hi;
            Al[m][kc] = lo;
        }
    }

    f32x4 acc[4][4];
#pragma unroll
    for (int m = 0; m < 4; ++m)
#pragma unroll
        for (int n = 0; n < 4; ++n)
            acc[m][n] = f32x4{0.f, 0.f, 0.f, 0.f};

#pragma unroll
    for (int ncl = 0; ncl < 4; ++ncl) {
        int nc = w * 4 + ncl;
        s8v Bh[2], Bl[2];
#pragma unroll
        for (int kc = 0; kc < 2; ++kc) {
            size_t base = ((size_t)((kc * 16 + nc) * 64 + l)) * 8;
            Bh[kc] = *(const s8v*)&W1h[base];
            Bl[kc] = *(const s8v*)&W1l[base];
        }
#pragma unroll
        for (int m = 0; m < 4; ++m) {
#pragma unroll
            for (int kc = 0; kc < 2; ++kc) {
                acc[m][ncl] = __builtin_amdgcn_mfma_f32_16x16x32_bf16(Ah[m][kc], Bh[kc], acc[m][ncl], 0, 0, 0);
                acc[m][ncl] = __builtin_amdgcn_mfma_f32_16x16x32_bf16(Ah[m][kc], Bl[kc], acc[m][ncl], 0, 0, 0);
                acc[m][ncl] = __builtin_amdgcn_mfma_f32_16x16x32_bf16(Al[m][kc], Bh[kc], acc[m][ncl], 0, 0, 0);
            }
        }
    }

    // bias + relu + cvt bf16 -> hidden LDS (C layout: col=c, row=g*4+r)
#pragma unroll
    for (int m = 0; m < 4; ++m) {
#pragma unroll
        for (int ncl = 0; ncl < 4; ++ncl) {
            int j = w * 64 + ncl * 16 + c;
            float bj = b1s[j];
#pragma unroll
            for (int r = 0; r < 4; ++r) {
                int e = m * 16 + g * 4 + r;
                float v = fmaxf(acc[m][ncl][r] + bj, 0.f);
                hid[e][j] = f2bf(v);
            }
        }
    }
    __syncthreads();

    // GEMM2: score[16 e][16 (8 valid)] = hid[w*16..][256] @ W2f
    f32x4 acc2 = f32x4{0.f, 0.f, 0.f, 0.f};
#pragma unroll
    for (int kc = 0; kc < 8; ++kc) {
        s8v a = *(const s8v*)&hid[w * 16 + c][kc * 32 + g * 8];
        s8v b = *(const s8v*)&W2f[(size_t)(kc * 64 + l) * 8];
        acc2 = __builtin_amdgcn_mfma_f32_16x16x32_bf16(a, b, acc2, 0, 0, 0);
    }
    if (c < 8) {
        float bb = b2[c];
#pragma unroll
        for (int r = 0; r < 4; ++r) {
            int ge = e0 + w * 16 + g * 4 + r;
            if (ge < E) mlp[(size_t)ge * 8 + c] = acc2[r] + bb;
        }
    }
}

// ---------------------------------------------------------------------------
// CSR build (unchanged)
// ---------------------------------------------------------------------------
__global__ void count_edges(const int* __restrict__ dst, int* counts, int E) {
    int e = blockIdx.x * 256 + threadIdx.x;
    if (e < E) atomicAdd(&counts[dst[e]], 1);
}

__global__ __launch_bounds__(1024) void scan_counts(const int* __restrict__ counts,
                                                    int* indptr, int* fill, int n) {
    __shared__ int sm[1024];
    __shared__ int carry_s;
    int t = threadIdx.x;
    if (t == 0) carry_s = 0;
    __syncthreads();
    for (int base = 0; base < n; base += 1024) {
        int i = base + t;
        int v = (i < n) ? counts[i] : 0;
        sm[t] = v;
        __syncthreads();
        for (int off = 1; off < 1024; off <<= 1) {
            int u = (t >= off) ? sm[t - off] : 0;
            __syncthreads();
            sm[t] += u;
            __syncthreads();
        }
        int carry = carry_s;
        int excl  = carry + sm[t] - v;
        if (i < n) { indptr[i] = excl; fill[i] = excl; }
        __syncthreads();
        if (t == 1023) carry_s = carry + sm[1023];
        __syncthreads();
    }
    if (t == 0) indptr[n] = carry_s;
}

__global__ void scatter_edges(const int* __restrict__ dst, int* fill,
                              int* edge_ids, int E) {
    int e = blockIdx.x * 256 + threadIdx.x;
    if (e < E) {
        int pos = atomicAdd(&fill[dst[e]], 1);
        edge_ids[pos] = e;
    }
}

// ---------------------------------------------------------------------------
// Per-node fused softmax + aggregation (unchanged)
// ---------------------------------------------------------------------------
__global__ __launch_bounds__(64) void node_aggregate(
        const float* __restrict__ Q, const float* __restrict__ K,
        const float* __restrict__ V, const float* __restrict__ mlp,
        const float* __restrict__ b2, const int* __restrict__ src,
        const int* __restrict__ indptr, const int* __restrict__ edge_ids,
        float* __restrict__ outp, int Nn) {
    int b = blockIdx.x;
    if (b >= Nn) return;
    int lane = threadIdx.x;
    int g = lane >> 3;
    float4 q4 = *(const float4*)&Q[(size_t)b * 256 + lane * 4];
    int beg = indptr[b], end = indptr[b + 1];
    float o0 = 0.f, o1 = 0.f, o2 = 0.f, o3 = 0.f;
    float den = 0.f;
    const float inv_sqrt = 0.17677669529663687f;  // 1/sqrt(32)
    for (int idx = beg; idx < end; ++idx) {
        int e = edge_ids[idx];
        int s = src[e];
        float4 k4 = *(const float4*)&K[(size_t)s * 256 + lane * 4];
        float4 v4 = *(const float4*)&V[(size_t)s * 256 + lane * 4];
        float part = q4.x * k4.x + q4.y * k4.y + q4.z * k4.z + q4.w * k4.w;
        part += __shfl_xor(part, 1, 64);
        part += __shfl_xor(part, 2, 64);
        part += __shfl_xor(part, 4, 64);
        float scv = part * inv_sqrt + mlp[(size_t)e * 8 + g];  // b2 folded into mlp
        float p = __expf(scv);
        den += p;
        o0 += p * v4.x; o1 += p * v4.y; o2 += p * v4.z; o3 += p * v4.w;
    }
    float invd = (end > beg) ? 1.f / den : 0.f;
    float4 ov = make_float4(o0 * invd, o1 * invd, o2 * invd, o3 * invd);
    *(float4*)&outp[(size_t)b * 256 + lane * 4] = ov;
}

// ---------------------------------------------------------------------------
extern "C" void kernel_launch(void* const* d_in, const int* in_sizes, int n_in,
                              void* d_out, int out_size, void* d_ws, size_t ws_size,
                              hipStream_t stream) {
    const float* h     = (const float*)d_in[0];
    const float* efeat = (const float*)d_in[1];
    const int*   src   = (const int*)d_in[2];
    const int*   dst   = (const int*)d_in[3];
    const float* Wq    = (const float*)d_in[4];
    const float* Wk    = (const float*)d_in[5];
    const float* Wv    = (const float*)d_in[6];
    const float* W1    = (const float*)d_in[7];
    const float* b1    = (const float*)d_in[8];
    const float* W2    = (const float*)d_in[9];
    const float* b2    = (const float*)d_in[10];
    const float* Wo    = (const float*)d_in[11];
    const float* bo    = (const float*)d_in[12];
    float* out = (float*)d_out;

    const int N = in_sizes[0] / 256;
    const int E = in_sizes[2];

    char* p = (char*)d_ws;
    auto carve = [&](size_t bytes) {
        char* r = p;
        p += (bytes + 255) & ~(size_t)255;
        return (void*)r;
    };
    float* Q      = (float*)carve((size_t)N * 256 * 4);
    float* Kp     = (float*)carve((size_t)N * 256 * 4);
    float* Vp     = (float*)carve((size_t)N * 256 * 4);
    float* mlp    = (float*)carve((size_t)E * 8 * 4);
    float* outp   = (float*)carve((size_t)N * 256 * 4);
    int* counts   = (int*)carve((size_t)N * 4);
    int* indptr   = (int*)carve((size_t)(N + 1) * 4);
    int* fill     = (int*)carve((size_t)N * 4);
    int* edge_ids = (int*)carve((size_t)E * 4);
    unsigned short* W1h = (unsigned short*)carve(16384 * 2);
    unsigned short* W1l = (unsigned short*)carve(16384 * 2);
    unsigned short* W2f = (unsigned short*)carve(4096 * 2);

    hipMemsetAsync(counts, 0, (size_t)N * 4, stream);

    prep_w1<<<64, 256, 0, stream>>>(W1, W1h, W1l);
    prep_w2<<<16, 256, 0, stream>>>(W2, W2f);

    dim3 gg((N + 63) / 64, 4);
    gemm256<<<gg, 256, 0, stream>>>(h, Wq, nullptr, Q, N);
    gemm256<<<gg, 256, 0, stream>>>(h, Wk, nullptr, Kp, N);
    gemm256<<<gg, 256, 0, stream>>>(h, Wv, nullptr, Vp, N);
    edge_mlp_mfma<<<(E + 63) / 64, 256, 0, stream>>>(efeat, W1h, W1l, W2f, b1, b2, mlp, E);
    count_edges<<<(E + 255) / 256, 256, 0, stream>>>(dst, counts, E);
    scan_counts<<<1, 1024, 0, stream>>>(counts, indptr, fill, N);
    scatter_edges<<<(E + 255) / 256, 256, 0, stream>>>(dst, fill, edge_ids, E);
    node_aggregate<<<N, 64, 0, stream>>>(Q, Kp, Vp, mlp, b2, src, indptr, edge_ids, outp, N);
    gemm256<<<gg, 256, 0, stream>>>(outp, Wo, bo, out, N);
}

// Round 3
// 1076.590 us; speedup vs baseline: 1.6986x; 1.1591x over previous
//
#include <hip/hip_runtime.h>
#include <math.h>

// Sizes fixed by problem: D=256, H=8, HD=32, FE=64. N, E from in_sizes.

typedef short s8v __attribute__((ext_vector_type(8)));   // 8 bf16 (4 VGPR)
typedef float f32x4 __attribute__((ext_vector_type(4))); // MFMA acc

__device__ inline unsigned short f2bf(float x) {
    unsigned int u = __float_as_uint(x);
    unsigned int r = u + 0x7FFFu + ((u >> 16) & 1u);  // RNE
    return (unsigned short)(r >> 16);
}
__device__ inline float bf2f(unsigned short b) {
    return __uint_as_float(((unsigned int)b) << 16);
}

// ---------------------------------------------------------------------------
// prep_split: fp32 array -> hi/lo bf16 arrays (vectorized, grid-stride).
// n4 = count/4 (count divisible by 4).
// ---------------------------------------------------------------------------
__global__ __launch_bounds__(256) void prep_split(const float* __restrict__ X,
                                                  unsigned short* __restrict__ Xh,
                                                  unsigned short* __restrict__ Xl,
                                                  int n4) {
    for (int i = blockIdx.x * 256 + threadIdx.x; i < n4; i += gridDim.x * 256) {
        float4 v = ((const float4*)X)[i];
        ushort4 hv, lv;
        float x[4] = {v.x, v.y, v.z, v.w};
        unsigned short hh[4], ll[4];
#pragma unroll
        for (int j = 0; j < 4; ++j) {
            hh[j] = f2bf(x[j]);
            ll[j] = f2bf(x[j] - bf2f(hh[j]));
        }
        hv.x = hh[0]; hv.y = hh[1]; hv.z = hh[2]; hv.w = hh[3];
        lv.x = ll[0]; lv.y = ll[1]; lv.z = ll[2]; lv.w = ll[3];
        ((ushort4*)Xh)[i] = hv;
        ((ushort4*)Xl)[i] = lv;
    }
}

// ---------------------------------------------------------------------------
// prep_w256: W (256x256 fp32) -> MFMA B-frag order, bf16 hi/lo split.
// idx = ((kc*16+nc)*64+lane)*8+i ; k = kc*32+(lane>>4)*8+i, col = nc*16+(lane&15)
// ---------------------------------------------------------------------------
__global__ void prep_w256(const float* __restrict__ W,
                          unsigned short* __restrict__ Wh,
                          unsigned short* __restrict__ Wl) {
    int f = blockIdx.x * 256 + threadIdx.x;  // 0..65535
    if (f >= 65536) return;
    int i    = f & 7;
    int lane = (f >> 3) & 63;
    int nc   = (f >> 9) & 15;
    int kc   = f >> 13;  // 0..7
    int k    = kc * 32 + (lane >> 4) * 8 + i;
    int col  = nc * 16 + (lane & 15);
    float v = W[k * 256 + col];
    unsigned short hb = f2bf(v);
    Wh[f] = hb;
    Wl[f] = f2bf(v - bf2f(hb));
}

// ---------------------------------------------------------------------------
// gemm_mfma: C[M x 256] = A[M x 256] @ W[256 x 256] (+bias), split-bf16 MFMA.
// Block: 64 rows, 4 waves; wave w -> cols w*64..w*64+63.
// Epilogue: optional fp32 out, optional bf16 out (stride/offset for KV pack).
// ---------------------------------------------------------------------------
__global__ __launch_bounds__(256) void gemm_mfma(
        const unsigned short* __restrict__ Ah, const unsigned short* __restrict__ Al,
        const unsigned short* __restrict__ Wh, const unsigned short* __restrict__ Wl,
        const float* __restrict__ bias,
        float* __restrict__ outF,
        unsigned short* __restrict__ outB, int ob_stride, int ob_off,
        int M) {
    int t = threadIdx.x;
    int w = t >> 6, l = t & 63;
    int c = l & 15, g = l >> 4;
    int row0 = blockIdx.x * 64;

    f32x4 acc[4][4];
#pragma unroll
    for (int m = 0; m < 4; ++m)
#pragma unroll
        for (int n = 0; n < 4; ++n) acc[m][n] = f32x4{0.f, 0.f, 0.f, 0.f};

#pragma unroll
    for (int kc = 0; kc < 8; ++kc) {
        s8v ah[4], al[4];
#pragma unroll
        for (int m = 0; m < 4; ++m) {
            int row = row0 + m * 16 + c;
            if (row < M) {
                size_t off = (size_t)row * 256 + kc * 32 + g * 8;
                ah[m] = *(const s8v*)&Ah[off];
                al[m] = *(const s8v*)&Al[off];
            } else {
                ah[m] = s8v{0, 0, 0, 0, 0, 0, 0, 0};
                al[m] = s8v{0, 0, 0, 0, 0, 0, 0, 0};
            }
        }
#pragma unroll
        for (int n = 0; n < 4; ++n) {
            int nc = w * 4 + n;
            size_t bo = ((size_t)(kc * 16 + nc) * 64 + l) * 8;
            s8v bh = *(const s8v*)&Wh[bo];
            s8v bl = *(const s8v*)&Wl[bo];
#pragma unroll
            for (int m = 0; m < 4; ++m) {
                acc[m][n] = __builtin_amdgcn_mfma_f32_16x16x32_bf16(ah[m], bh, acc[m][n], 0, 0, 0);
                acc[m][n] = __builtin_amdgcn_mfma_f32_16x16x32_bf16(ah[m], bl, acc[m][n], 0, 0, 0);
                acc[m][n] = __builtin_amdgcn_mfma_f32_16x16x32_bf16(al[m], bh, acc[m][n], 0, 0, 0);
            }
        }
    }

    // C layout: col = c (lane&15), row-in-tile = g*4 + r
#pragma unroll
    for (int m = 0; m < 4; ++m) {
#pragma unroll
        for (int n = 0; n < 4; ++n) {
            int col = w * 64 + n * 16 + c;
            float bb = bias ? bias[col] : 0.f;
#pragma unroll
            for (int r = 0; r < 4; ++r) {
                int row = row0 + m * 16 + g * 4 + r;
                if (row >= M) continue;
                float v = acc[m][n][r] + bb;
                if (outF) outF[(size_t)row * 256 + col] = v;
                if (outB) outB[(size_t)row * ob_stride + ob_off + col] = f2bf(v);
            }
        }
    }
}

// ---------------------------------------------------------------------------
// W1/W2 prep for edge MLP (unchanged, verified layouts)
// ---------------------------------------------------------------------------
__global__ void prep_w1(const float* __restrict__ W1,
                        unsigned short* __restrict__ W1h,
                        unsigned short* __restrict__ W1l) {
    int f = blockIdx.x * 256 + threadIdx.x;  // 0..16383
    if (f >= 16384) return;
    int i    = f & 7;
    int lane = (f >> 3) & 63;
    int nc   = (f >> 9) & 15;
    int kc   = (f >> 13) & 1;
    int k    = kc * 32 + (lane >> 4) * 8 + i;
    int col  = nc * 16 + (lane & 15);
    float v = W1[k * 256 + col];
    unsigned short hb = f2bf(v);
    W1h[f] = hb;
    W1l[f] = f2bf(v - bf2f(hb));
}

__global__ void prep_w2(const float* __restrict__ W2,
                        unsigned short* __restrict__ W2f) {
    int f = blockIdx.x * 256 + threadIdx.x;  // 0..4095
    if (f >= 4096) return;
    int i    = f & 7;
    int lane = (f >> 3) & 63;
    int kc   = (f >> 9) & 7;
    int k    = kc * 32 + (lane >> 4) * 8 + i;
    int col  = lane & 15;
    float v = (col < 8) ? W2[k * 8 + col] : 0.f;
    W2f[f] = f2bf(v);
}

// ---------------------------------------------------------------------------
// Edge MLP via MFMA, writing scores to CSR position (pos_of_edge).
// ---------------------------------------------------------------------------
__global__ __launch_bounds__(256) void edge_mlp_mfma(
        const float* __restrict__ efeat,
        const unsigned short* __restrict__ W1h,
        const unsigned short* __restrict__ W1l,
        const unsigned short* __restrict__ W2f,
        const float* __restrict__ b1, const float* __restrict__ b2,
        const int* __restrict__ pos_of_edge,
        float* __restrict__ mlp_csr, int E) {
    __shared__ float efs[64][68];
    __shared__ unsigned short hid[64][264];
    __shared__ float b1s[256];
    int t  = threadIdx.x;
    int e0 = blockIdx.x * 64;

    {
        int row = t >> 2, cq = (t & 3) * 16;
        int ge = e0 + row;
#pragma unroll
        for (int u = 0; u < 4; ++u) {
            float4 v;
            if (ge < E) v = *(const float4*)&efeat[(size_t)ge * 64 + cq + u * 4];
            else        v = make_float4(0.f, 0.f, 0.f, 0.f);
            *(float4*)&efs[row][cq + u * 4] = v;
        }
        b1s[t] = b1[t];
    }
    __syncthreads();

    int w = t >> 6;
    int l = t & 63;
    int c = l & 15, g = l >> 4;

    s8v Ah[4][2], Al[4][2];
#pragma unroll
    for (int m = 0; m < 4; ++m) {
        int row = m * 16 + c;
#pragma unroll
        for (int kc = 0; kc < 2; ++kc) {
            const float* p = &efs[row][kc * 32 + g * 8];
            float x[8];
            *(float4*)&x[0] = *(const float4*)&p[0];
            *(float4*)&x[4] = *(const float4*)&p[4];
            s8v hi, lo;
#pragma unroll
            for (int i = 0; i < 8; ++i) {
                unsigned short hb = f2bf(x[i]);
                hi[i] = (short)hb;
                lo[i] = (short)f2bf(x[i] - bf2f(hb));
            }
            Ah[m][kc] = hi;
            Al[m][kc] = lo;
        }
    }

    f32x4 acc[4][4];
#pragma unroll
    for (int m = 0; m < 4; ++m)
#pragma unroll
        for (int n = 0; n < 4; ++n) acc[m][n] = f32x4{0.f, 0.f, 0.f, 0.f};

#pragma unroll
    for (int ncl = 0; ncl < 4; ++ncl) {
        int nc = w * 4 + ncl;
        s8v Bh[2], Bl[2];
#pragma unroll
        for (int kc = 0; kc < 2; ++kc) {
            size_t base = ((size_t)((kc * 16 + nc) * 64 + l)) * 8;
            Bh[kc] = *(const s8v*)&W1h[base];
            Bl[kc] = *(const s8v*)&W1l[base];
        }
#pragma unroll
        for (int m = 0; m < 4; ++m) {
#pragma unroll
            for (int kc = 0; kc < 2; ++kc) {
                acc[m][ncl] = __builtin_amdgcn_mfma_f32_16x16x32_bf16(Ah[m][kc], Bh[kc], acc[m][ncl], 0, 0, 0);
                acc[m][ncl] = __builtin_amdgcn_mfma_f32_16x16x32_bf16(Ah[m][kc], Bl[kc], acc[m][ncl], 0, 0, 0);
                acc[m][ncl] = __builtin_amdgcn_mfma_f32_16x16x32_bf16(Al[m][kc], Bh[kc], acc[m][ncl], 0, 0, 0);
            }
        }
    }

#pragma unroll
    for (int m = 0; m < 4; ++m) {
#pragma unroll
        for (int ncl = 0; ncl < 4; ++ncl) {
            int j = w * 64 + ncl * 16 + c;
            float bj = b1s[j];
#pragma unroll
            for (int r = 0; r < 4; ++r) {
                int e = m * 16 + g * 4 + r;
                float v = fmaxf(acc[m][ncl][r] + bj, 0.f);
                hid[e][j] = f2bf(v);
            }
        }
    }
    __syncthreads();

    f32x4 acc2 = f32x4{0.f, 0.f, 0.f, 0.f};
#pragma unroll
    for (int kc = 0; kc < 8; ++kc) {
        s8v a = *(const s8v*)&hid[w * 16 + c][kc * 32 + g * 8];
        s8v b = *(const s8v*)&W2f[(size_t)(kc * 64 + l) * 8];
        acc2 = __builtin_amdgcn_mfma_f32_16x16x32_bf16(a, b, acc2, 0, 0, 0);
    }
    if (c < 8) {
        float bb = b2[c];
#pragma unroll
        for (int r = 0; r < 4; ++r) {
            int ge = e0 + w * 16 + g * 4 + r;
            if (ge < E) {
                int p = pos_of_edge[ge];
                mlp_csr[(size_t)p * 8 + c] = acc2[r] + bb;
            }
        }
    }
}

// ---------------------------------------------------------------------------
// CSR build
// ---------------------------------------------------------------------------
__global__ void count_edges(const int* __restrict__ dst, int* counts, int E) {
    int e = blockIdx.x * 256 + threadIdx.x;
    if (e < E) atomicAdd(&counts[dst[e]], 1);
}

__global__ __launch_bounds__(1024) void scan_counts(const int* __restrict__ counts,
                                                    int* indptr, int* fill, int n) {
    __shared__ int sm[1024];
    int t = threadIdx.x;
    int per = (n + 1023) / 1024;
    int b = t * per, e = min(b + per, n);
    int s = 0;
    for (int i = b; i < e; ++i) s += counts[i];
    sm[t] = s;
    __syncthreads();
    for (int off = 1; off < 1024; off <<= 1) {
        int u = (t >= off) ? sm[t - off] : 0;
        __syncthreads();
        sm[t] += u;
        __syncthreads();
    }
    int excl = t ? sm[t - 1] : 0;
    for (int i = b; i < e; ++i) {
        indptr[i] = excl;
        fill[i]   = excl;
        excl += counts[i];
    }
    if (t == 1023) indptr[n] = sm[1023];
}

__global__ void scatter_edges(const int* __restrict__ dst, const int* __restrict__ src,
                              int* fill, int* pos_of_edge, int* src_s, int E) {
    int e = blockIdx.x * 256 + threadIdx.x;
    if (e < E) {
        int pos = atomicAdd(&fill[dst[e]], 1);
        pos_of_edge[e] = pos;
        src_s[pos] = src[e];
    }
}

// ---------------------------------------------------------------------------
// Per-node fused softmax + aggregation. 4 waves/block (1 node per wave),
// bf16 KV gather with 2-deep software pipeline, CSR-direct arrays.
// ---------------------------------------------------------------------------
__global__ __launch_bounds__(256) void node_aggregate2(
        const float* __restrict__ Q, const unsigned short* __restrict__ KVb,
        const float* __restrict__ mlp_csr, const int* __restrict__ src_s,
        const int* __restrict__ indptr, float* __restrict__ outp, int Nn) {
    int node = blockIdx.x * 4 + (threadIdx.x >> 6);
    if (node >= Nn) return;
    int l = threadIdx.x & 63;
    int g = l >> 3;
    float4 q4 = *(const float4*)&Q[(size_t)node * 256 + l * 4];
    int beg = indptr[node], end = indptr[node + 1];
    float o0 = 0.f, o1 = 0.f, o2 = 0.f, o3 = 0.f, den = 0.f;
    const float inv_sqrt = 0.17677669529663687f;  // 1/sqrt(32)

    if (beg < end) {
        int last = end - 1;
        int s  = src_s[beg];
        int sn = src_s[min(beg + 1, last)];
        ushort4 k4 = *(const ushort4*)&KVb[(size_t)s * 512 + l * 4];
        ushort4 v4 = *(const ushort4*)&KVb[(size_t)s * 512 + 256 + l * 4];
        for (int idx = beg; idx < end; ++idx) {
            int scur = sn;
            sn = src_s[min(idx + 2, last)];
            ushort4 k4n = *(const ushort4*)&KVb[(size_t)scur * 512 + l * 4];
            ushort4 v4n = *(const ushort4*)&KVb[(size_t)scur * 512 + 256 + l * 4];
            float mv = mlp_csr[(size_t)idx * 8 + g];
            float part = q4.x * bf2f(k4.x) + q4.y * bf2f(k4.y) +
                         q4.z * bf2f(k4.z) + q4.w * bf2f(k4.w);
            part += __shfl_xor(part, 1, 64);
            part += __shfl_xor(part, 2, 64);
            part += __shfl_xor(part, 4, 64);
            float p = __expf(part * inv_sqrt + mv);
            den += p;
            o0 += p * bf2f(v4.x); o1 += p * bf2f(v4.y);
            o2 += p * bf2f(v4.z); o3 += p * bf2f(v4.w);
            k4 = k4n; v4 = v4n;
        }
    }
    float invd = (end > beg) ? 1.f / den : 0.f;
    float4 ov = make_float4(o0 * invd, o1 * invd, o2 * invd, o3 * invd);
    *(float4*)&outp[(size_t)node * 256 + l * 4] = ov;
}

// ---------------------------------------------------------------------------
extern "C" void kernel_launch(void* const* d_in, const int* in_sizes, int n_in,
                              void* d_out, int out_size, void* d_ws, size_t ws_size,
                              hipStream_t stream) {
    const float* h     = (const float*)d_in[0];
    const float* efeat = (const float*)d_in[1];
    const int*   src   = (const int*)d_in[2];
    const int*   dst   = (const int*)d_in[3];
    const float* Wq    = (const float*)d_in[4];
    const float* Wk    = (const float*)d_in[5];
    const float* Wv    = (const float*)d_in[6];
    const float* W1    = (const float*)d_in[7];
    const float* b1    = (const float*)d_in[8];
    const float* W2    = (const float*)d_in[9];
    const float* b2    = (const float*)d_in[10];
    const float* Wo    = (const float*)d_in[11];
    const float* bo    = (const float*)d_in[12];
    float* out = (float*)d_out;

    const int N = in_sizes[0] / 256;
    const int E = in_sizes[2];

    char* p = (char*)d_ws;
    auto carve = [&](size_t bytes) {
        char* r = p;
        p += (bytes + 255) & ~(size_t)255;
        return (void*)r;
    };
    unsigned short* h_hi = (unsigned short*)carve((size_t)N * 256 * 2);  // reused for outp
    unsigned short* h_lo = (unsigned short*)carve((size_t)N * 256 * 2);
    float* Q      = (float*)carve((size_t)N * 256 * 4);
    unsigned short* KVb = (unsigned short*)carve((size_t)N * 512 * 2);
    float* mlp_csr = (float*)carve((size_t)E * 8 * 4);
    float* outp   = (float*)carve((size_t)N * 256 * 4);
    int* counts   = (int*)carve((size_t)N * 4);
    int* indptr   = (int*)carve((size_t)(N + 1) * 4);
    int* fill     = (int*)carve((size_t)N * 4);
    int* pos_of_edge = (int*)carve((size_t)E * 4);
    int* src_s    = (int*)carve((size_t)E * 4);
    unsigned short* WqH = (unsigned short*)carve(65536 * 2);
    unsigned short* WqL = (unsigned short*)carve(65536 * 2);
    unsigned short* WkH = (unsigned short*)carve(65536 * 2);
    unsigned short* WkL = (unsigned short*)carve(65536 * 2);
    unsigned short* WvH = (unsigned short*)carve(65536 * 2);
    unsigned short* WvL = (unsigned short*)carve(65536 * 2);
    unsigned short* WoH = (unsigned short*)carve(65536 * 2);
    unsigned short* WoL = (unsigned short*)carve(65536 * 2);
    unsigned short* W1h = (unsigned short*)carve(16384 * 2);
    unsigned short* W1l = (unsigned short*)carve(16384 * 2);
    unsigned short* W2f = (unsigned short*)carve(4096 * 2);

    hipMemsetAsync(counts, 0, (size_t)N * 4, stream);

    // weight preps
    prep_w256<<<256, 256, 0, stream>>>(Wq, WqH, WqL);
    prep_w256<<<256, 256, 0, stream>>>(Wk, WkH, WkL);
    prep_w256<<<256, 256, 0, stream>>>(Wv, WvH, WvL);
    prep_w256<<<256, 256, 0, stream>>>(Wo, WoH, WoL);
    prep_w1<<<64, 256, 0, stream>>>(W1, W1h, W1l);
    prep_w2<<<16, 256, 0, stream>>>(W2, W2f);

    // CSR build
    count_edges<<<(E + 255) / 256, 256, 0, stream>>>(dst, counts, E);
    scan_counts<<<1, 1024, 0, stream>>>(counts, indptr, fill, N);
    scatter_edges<<<(E + 255) / 256, 256, 0, stream>>>(dst, src, fill, pos_of_edge, src_s, E);

    // projections
    int gx = (N + 63) / 64;
    prep_split<<<2048, 256, 0, stream>>>(h, h_hi, h_lo, N * 64);  // N*256/4
    gemm_mfma<<<gx, 256, 0, stream>>>(h_hi, h_lo, WqH, WqL, nullptr, Q, nullptr, 0, 0, N);
    gemm_mfma<<<gx, 256, 0, stream>>>(h_hi, h_lo, WkH, WkL, nullptr, nullptr, KVb, 512, 0, N);
    gemm_mfma<<<gx, 256, 0, stream>>>(h_hi, h_lo, WvH, WvL, nullptr, nullptr, KVb, 512, 256, N);

    // edge scores
    edge_mlp_mfma<<<(E + 63) / 64, 256, 0, stream>>>(efeat, W1h, W1l, W2f, b1, b2,
                                                     pos_of_edge, mlp_csr, E);

    // fused softmax + aggregation
    node_aggregate2<<<(N + 3) / 4, 256, 0, stream>>>(Q, KVb, mlp_csr, src_s, indptr, outp, N);

    // output projection (reuse h_hi/h_lo buffers)
    prep_split<<<2048, 256, 0, stream>>>(outp, h_hi, h_lo, N * 64);
    gemm_mfma<<<gx, 256, 0, stream>>>(h_hi, h_lo, WoH, WoL, bo, out, nullptr, 0, 0, N);
}